// Round 1
// baseline (183.333 us; speedup 1.0000x reference)
//
#include <hip/hip_runtime.h>
#include <hip/hip_bf16.h>

#define SEQ_LEN  8192
#define HIDDEN   1024
#define NUM_SPANS 4096
#define MAX_W    32
#define NEG_INF  -1e9f

// One block per span, 256 threads.
// Phase 1: scores[w] = dot(emb[start+w], attn_w) + b  (8 lanes per position)
// Phase 2: masked softmax over 32 positions (first 32 lanes, shuffle reduce)
// Phase 3: out = [emb[start] | emb[end] | sum_w wt[w]*emb[start+w]]  (float4 coalesced)
__global__ __launch_bounds__(256) void span_repr_kernel(
    const float* __restrict__ emb,      // (SEQ_LEN, HIDDEN)
    const int* __restrict__ starts,     // (NUM_SPANS,)
    const int* __restrict__ ends,       // (NUM_SPANS,)
    const float* __restrict__ attn_w,   // (HIDDEN,)
    const float* __restrict__ attn_b,   // (1,)
    float* __restrict__ out)            // (NUM_SPANS, 3*HIDDEN)
{
    const int s   = blockIdx.x;
    const int tid = threadIdx.x;

    __shared__ float s_scores[MAX_W];
    __shared__ float s_wt[MAX_W];

    const int start = starts[s];
    const int end   = ends[s];
    const float bias = attn_b[0];

    // ---------- Phase 1: scores ----------
    const int w = tid >> 3;   // 0..31 position within span
    const int g = tid & 7;    // 0..7 chunk of 128 elements
    const int pos = start + w;
    const bool valid = (pos <= end);

    float partial = 0.0f;
    if (valid) {
        const int pc = min(pos, SEQ_LEN - 1);
        const float4* __restrict__ row = (const float4*)(emb + (size_t)pc * HIDDEN);
        const float4* __restrict__ wv  = (const float4*)attn_w;
        const int base = g * 32;  // float4 index: g*128 floats
        #pragma unroll
        for (int i = 0; i < 32; ++i) {
            float4 a = row[base + i];
            float4 b = wv[base + i];
            partial += a.x * b.x + a.y * b.y + a.z * b.z + a.w * b.w;
        }
    }
    // reduce the 8 chunk-partials (contiguous lanes within one wave)
    partial += __shfl_down(partial, 4, 8);
    partial += __shfl_down(partial, 2, 8);
    partial += __shfl_down(partial, 1, 8);
    if (g == 0) s_scores[w] = valid ? (partial + bias) : NEG_INF;
    __syncthreads();

    // ---------- Phase 2: masked softmax over 32 positions ----------
    if (tid < 32) {
        float sc = s_scores[tid];
        float m = sc;
        #pragma unroll
        for (int off = 16; off > 0; off >>= 1)
            m = fmaxf(m, __shfl_xor(m, off, 32));
        float e = expf(sc - m);         // invalid: exp(-1e9 - m) == 0.0f
        float sum = e;
        #pragma unroll
        for (int off = 16; off > 0; off >>= 1)
            sum += __shfl_xor(sum, off, 32);
        s_wt[tid] = e / sum;
    }
    __syncthreads();

    // ---------- Phase 3: outputs ----------
    // out row layout: [start_emb (1024) | end_emb (1024) | attn_out (1024)]
    float4* __restrict__ out4 = (float4*)(out + (size_t)s * (3 * HIDDEN));
    const float4* __restrict__ srow = (const float4*)(emb + (size_t)start * HIDDEN);
    const float4* __restrict__ erow = (const float4*)(emb + (size_t)min(end, SEQ_LEN - 1) * HIDDEN);

    out4[tid]       = srow[tid];   // 256 float4 = 1024 floats, fully coalesced
    out4[256 + tid] = erow[tid];

    float4 acc = make_float4(0.f, 0.f, 0.f, 0.f);
    const int wmax = end - start;  // inclusive width-1, 0..31
    for (int ww = 0; ww <= wmax; ++ww) {
        const float wt = s_wt[ww];
        const float4* __restrict__ row = (const float4*)(emb + (size_t)(start + ww) * HIDDEN);
        float4 a = row[tid];
        acc.x += wt * a.x;
        acc.y += wt * a.y;
        acc.z += wt * a.z;
        acc.w += wt * a.w;
    }
    out4[512 + tid] = acc;
}

extern "C" void kernel_launch(void* const* d_in, const int* in_sizes, int n_in,
                              void* d_out, int out_size, void* d_ws, size_t ws_size,
                              hipStream_t stream) {
    const float* emb    = (const float*)d_in[0];
    const int*   starts = (const int*)d_in[1];
    const int*   ends   = (const int*)d_in[2];
    const float* attn_w = (const float*)d_in[3];
    const float* attn_b = (const float*)d_in[4];
    float* out = (float*)d_out;

    span_repr_kernel<<<NUM_SPANS, 256, 0, stream>>>(emb, starts, ends, attn_w, attn_b, out);
}